// Round 3
// baseline (172.691 us; speedup 1.0000x reference)
//
#include <hip/hip_runtime.h>

// MixSelfAttention (B=2, L=1024, H=8, E=64), float32 in/out. 5 dispatches:
//   D1 d1: k1 circular-corr partials, 2048 blocks (bh x eg x tc x tauhalf),
//          256 thr = 4 t-subchunks x 64 tau-grp, 8 taus/thread (acc32+wnd32 regs
//          -> compiler can pipeline; was 16 taus = 128 regs vs 96 alloc = stalls),
//          XOR8-swizzled LDS (conflict-free at stride-8 window reads),
//          in-block sub-combine -> acp[bh][eg][tc][tau][4e] raw partials (16 MB)
//          | kw tile-transpose W -> Wt[2048][1024] (blocks 2048..2559)
//   D2a: 512 blocks x 256 thr; t: tc-combine+square+e-sum -> amp[16][1024]
//        tf: row norms -> ampTF[16][1024]
//   D2b: 32 blocks x 64 thr; single-wave top-35 -> St / Stf
//   D3 d3: kb direct-Wt WVp partials, LDS-staged W-rows (0..1151)
//          | k4 scores+softmax -> P (1152..1663)
//   D4 k6: per-bh blocks, 512 thr; Wv=sum_mc WVp staged in LDS + transposed P

#define NTOP 35
#define NJ 70
#define LLMIN (-0x7FFFFFFFFFFFFFFFLL - 1)

static __device__ __forceinline__ void fma4(float4& a, float4 q, float4 k) {
  a.x = fmaf(q.x,k.x,a.x); a.y = fmaf(q.y,k.y,a.y);
  a.z = fmaf(q.z,k.z,a.z); a.w = fmaf(q.w,k.w,a.w);
}
static __device__ __forceinline__ void fadd4(float4& a, float4 b) {
  a.x += b.x; a.y += b.y; a.z += b.z; a.w += b.w;
}

// single-wave top-35 (64-thread block), vals[1024] ready, jax tie-break
static __device__ __forceinline__ void wave_top35(const float* vals, int* out) {
  int lane = threadIdx.x;
  long long kreg[16];
  long long lmax = LLMIN;
  #pragma unroll
  for (int s = 0; s < 16; ++s) {
    int l = (s << 6) + lane;
    long long key = ((long long)(int)__float_as_uint(vals[l]) << 32)
                    | (unsigned int)(1023 - l);
    kreg[s] = key;
    lmax = key > lmax ? key : lmax;
  }
  for (int it = 0; it < NTOP; ++it) {
    long long g = lmax;
    #pragma unroll
    for (int off = 1; off < 64; off <<= 1) {
      long long o = __shfl_xor(g, off);
      g = o > g ? o : g;
    }
    if (lane == 0) out[it] = 1023 - (int)(g & 0xFFFFFFFFLL);
    if (lmax == g) {
      lmax = LLMIN;
      #pragma unroll
      for (int s = 0; s < 16; ++s) {
        if (kreg[s] == g) kreg[s] = LLMIN;
        lmax = kreg[s] > lmax ? kreg[s] : lmax;
      }
    }
  }
}

// XOR8 swizzle: conflict-free for stride-1 (staging) AND stride-8 (window reads:
// r = A + 8*tg -> (r>>3)&7 = (A>>3 + tg)&7 varies per lane -> 8 distinct quads
// per 8-lane phase). Same function on write and read side.
static __device__ __forceinline__ int qsw(int r) { return r ^ ((r >> 3) & 7); }

// ---------------- D1: k1 (2048 blocks) | kw (512 blocks), 256 thr ----------------
__global__ __launch_bounds__(256) void d1_prep(
    const float* __restrict__ q, const float* __restrict__ k,
    const float* __restrict__ w,
    float* __restrict__ Wt, float* __restrict__ acp) {
  __shared__ float smem[5200];          // 20.8 KB: QP 1024 f4 + Ks 256 f4 / kw tile
  int bid = blockIdx.x;
  int tid = threadIdx.x;
  if (bid < 2048) {                     // ---- k1: (bh, eg, tc, th) ----
    int bh = bid & 15;  int eg = (bid >> 4) & 15;
    int tc = (bid >> 8) & 3;  int th = bid >> 10;
    int b = bh >> 3, h = bh & 7;
    float4* QP = reinterpret_cast<float4*>(smem);        // 1024, XOR8 swizzle
    float4* Ks = QP + 1024;                              // 256 (this tc's t's)
    const float* qb  = q + (size_t)b*524288 + h*64 + eg*4;
    const float* kbp = k + (size_t)b*524288 + h*64 + eg*4;
    for (int r = tid; r < 1024; r += 256)
      QP[qsw(r)] = *reinterpret_cast<const float4*>(qb + (size_t)r*512);
    Ks[tid] = *reinterpret_cast<const float4*>(kbp + (size_t)((tc << 8) + tid)*512);
    __syncthreads();
    int sub = tid >> 6, tg = tid & 63;  // 4 t-subchunks x 64 tau-groups
    int tau0 = (th << 9) + (tg << 3);   // 8 taus per thread
    int tstart = (tc << 8) + (sub << 6);// absolute t in [tstart, tstart+64)
    float4 acc[8], wnd[8];
    #pragma unroll
    for (int i = 0; i < 8; ++i) {
      acc[i] = make_float4(0,0,0,0);
      int r = (tstart + tau0 + i) & 1023;
      wnd[i] = QP[qsw(r)];
    }
    int ksb = sub << 6;
    for (int t8 = 0; t8 < 64; t8 += 8) {
      #pragma unroll
      for (int s = 0; s < 8; ++s) {
        float4 kv = Ks[ksb + t8 + s];
        #pragma unroll
        for (int i = 0; i < 8; ++i)
          fma4(acc[i], wnd[(s + i) & 7], kv);   // acc FIXED per tau tau0+i
        int rn = (tstart + t8 + s + tau0 + 8) & 1023;
        wnd[s] = QP[qsw(rn)];                   // overwrite slot t&7
      }
    }
    __syncthreads();                    // QP/Ks dead; reuse for combine tree
    float4* xb = reinterpret_cast<float4*>(smem);   // 1300 f4 avail; use 1152
    // Level 1 (sub 2->0, 3->1), all 8 f4 at once, rows of 9 f4
    if (sub >= 2) {
      float4* rp = xb + (sub - 2)*576 + tg*9;
      #pragma unroll
      for (int i = 0; i < 8; ++i) rp[i] = acc[i];
    }
    __syncthreads();
    if (sub < 2) {
      const float4* rp = xb + sub*576 + tg*9;
      #pragma unroll
      for (int i = 0; i < 8; ++i) fadd4(acc[i], rp[i]);
    }
    __syncthreads();
    // Level 2 (sub 1 -> 0)
    if (sub == 1) {
      float4* rp = xb + tg*9;
      #pragma unroll
      for (int i = 0; i < 8; ++i) rp[i] = acc[i];
    }
    __syncthreads();
    if (sub == 0) {
      const float4* rp = xb + tg*9;
      #pragma unroll
      for (int i = 0; i < 8; ++i) fadd4(acc[i], rp[i]);
      // raw 4e partials for this (tc, tau-half) chunk
      float4* op = reinterpret_cast<float4*>(acp)
                 + (((size_t)((bh*16 + eg)*4 + tc)) << 10) + (th << 9) + (tg << 3);
      #pragma unroll
      for (int i = 0; i < 8; ++i) op[i] = acc[i];
    }
  } else {                              // ---- kw ----
    int wid = bid - 2048;
    int c0 = (wid & 31) << 6, r0 = (wid >> 5) << 6;
    float* tile = smem;                 // 64*65 floats
    #pragma unroll
    for (int s = 0; s < 16; ++s) {
      int idx = tid + (s << 8);
      int r = idx >> 6, c = idx & 63;
      tile[r*65 + c] = w[(size_t)(r0 + r)*2048 + c0 + c];
    }
    __syncthreads();
    #pragma unroll
    for (int s = 0; s < 16; ++s) {
      int idx = tid + (s << 8);
      int c = idx >> 6, r = idx & 63;
      Wt[(size_t)(c0 + c)*1024 + r0 + r] = tile[r*65 + c];
    }
  }
}

// ---------------- D2a: amp / tf-norm reduction, 512 blocks x 256 thr ----------------
__global__ __launch_bounds__(256) void d2a_amp(
    const float* __restrict__ acp, const float* __restrict__ tfq,
    float* __restrict__ amp, float* __restrict__ ampTF) {
  __shared__ float red[256];
  int bid = blockIdx.x;
  int tid = threadIdx.x;
  int lane = tid & 63, g = tid >> 6;     // 4 e-groups / 4 row-quarters
  if (bid < 256) {                        // ---- t: tc-combine + square + e-sum ----
    int bh = bid >> 4, tg = bid & 15;
    int tau = (tg << 6) + lane;
    const float4* A = reinterpret_cast<const float4*>(acp);
    float s = 0.f;
    #pragma unroll
    for (int eg4 = 0; eg4 < 4; ++eg4) {
      int eg = (g << 2) + eg4;
      const float4* E = A + (((size_t)(bh*16 + eg)) << 12);
      float4 c0 = E[tau], c1 = E[1024+tau], c2 = E[2048+tau], c3 = E[3072+tau];
      float x = c0.x+c1.x+c2.x+c3.x;
      float y = c0.y+c1.y+c2.y+c3.y;
      float z = c0.z+c1.z+c2.z+c3.z;
      float w = c0.w+c1.w+c2.w+c3.w;
      s += x*x + y*y + z*z + w*w;
    }
    red[tid] = s;
    __syncthreads();
    if (g == 0)
      amp[bh*1024 + tau] = red[lane] + red[64+lane] + red[128+lane] + red[192+lane];
  } else {                                // ---- tf: row norms ----
    int wid = bid - 256;
    int bh = wid >> 4, lg = wid & 15;
    int b = bh >> 3, h = bh & 7;
    int l = (lg << 6) + lane;
    const float4* p = reinterpret_cast<const float4*>(
        tfq + (((size_t)(b*1024 + l)*8 + h) << 6)) + (g << 2);
    float s = 0.f;
    #pragma unroll
    for (int i = 0; i < 4; ++i) {
      float4 vv = p[i];
      s += vv.x*vv.x + vv.y*vv.y + vv.z*vv.z + vv.w*vv.w;
    }
    red[tid] = s;
    __syncthreads();
    if (g == 0)
      ampTF[bh*1024 + l] = red[lane] + red[64+lane] + red[128+lane] + red[192+lane];
  }
}

// ---------------- D2b: top-35 both branches, 32 blocks x 1 wave ----------------
__global__ __launch_bounds__(64) void d2b_topk(
    const float* __restrict__ amp, const float* __restrict__ ampTF,
    int* __restrict__ St, int* __restrict__ Stf) {
  __shared__ float vals[1024];
  int bid = blockIdx.x;
  int tid = threadIdx.x;
  bool isT = bid < 16;
  int bh = isT ? bid : bid - 16;
  const float* src = (isT ? amp : ampTF) + bh*1024;
  #pragma unroll
  for (int s = 0; s < 16; ++s) vals[(s << 6) + tid] = src[(s << 6) + tid];
  __syncthreads();
  wave_top35(vals, (isT ? St : Stf) + bh*40);
}

// ---------------- D3: kb (LDS-staged Wt rows) | k4 ----------------
__global__ __launch_bounds__(256) void d3_mix(
    const float* __restrict__ q, const float* __restrict__ k,
    const float* __restrict__ tfq,
    const float* __restrict__ Wt, const float* __restrict__ bias,
    const float* __restrict__ values,
    const int* __restrict__ St, const int* __restrict__ Stf,
    float* __restrict__ WVp, float* __restrict__ P) {
  __shared__ float4 smbuf[1712];        // 27392 B (k4); kb uses first 8 KB
  float* f = reinterpret_cast<float*>(smbuf);
  int bid = blockIdx.x;
  int tid = threadIdx.x;
  if (bid < 1152) {                     // ---- kb: WVp partial, LDS-staged rows ----
    int jq = bid / 64;                  // 0..17
    int rem = bid - jq*64;
    int bh = rem >> 2, mc = rem & 3;
    int b = bh >> 3, h = bh & 7;
    int j0 = jq << 2;
    int mbase = mc << 8;
    float* rows = f + 1024;             // 4 rows x 256 m-chunk = 4 KB
    #pragma unroll
    for (int x = 0; x < 4; ++x) {
      int j = j0 + x;
      const float* pj;
      if (j < NTOP)      pj = Wt + (size_t)St [bh*40 + j]*1024;
      else if (j < NJ)   pj = Wt + (size_t)(1024 + Stf[bh*40 + j-NTOP])*1024;
      else if (j == NJ)  pj = bias;
      else               pj = Wt;       // j==71: garbage, zeroed in epilogue
      rows[(x << 8) + tid] = pj[mbase + tid];
    }
    __syncthreads();
    int d = tid & 63, mp = tid >> 6;    // wave mp owns contiguous m-chunk of 64
    float a0=0.f, a1=0.f, a2=0.f, a3=0.f;
    const float4* r4 = reinterpret_cast<const float4*>(rows);
    const float* vbase = values
        + (((size_t)(b*1024 + mbase + (mp << 6))*8 + h) << 6) + d;
    #pragma unroll 4
    for (int i4 = 0; i4 < 16; ++i4) {
      float4 w0 = r4[       (mp << 4) + i4];
      float4 w1 = r4[ 64  + (mp << 4) + i4];
      float4 w2 = r4[128  + (mp << 4) + i4];
      float4 w3 = r4[192  + (mp << 4) + i4];
      float v0 = vbase[(size_t)((i4 << 2) + 0)*512];
      float v1 = vbase[(size_t)((i4 << 2) + 1)*512];
      float v2 = vbase[(size_t)((i4 << 2) + 2)*512];
      float v3 = vbase[(size_t)((i4 << 2) + 3)*512];
      a0 = fmaf(w0.x,v0,a0); a0 = fmaf(w0.y,v1,a0);
      a0 = fmaf(w0.z,v2,a0); a0 = fmaf(w0.w,v3,a0);
      a1 = fmaf(w1.x,v0,a1); a1 = fmaf(w1.y,v1,a1);
      a1 = fmaf(w1.z,v2,a1); a1 = fmaf(w1.w,v3,a1);
      a2 = fmaf(w2.x,v0,a2); a2 = fmaf(w2.y,v1,a2);
      a2 = fmaf(w2.z,v2,a2); a2 = fmaf(w2.w,v3,a2);
      a3 = fmaf(w3.x,v0,a3); a3 = fmaf(w3.y,v1,a3);
      a3 = fmaf(w3.z,v2,a3); a3 = fmaf(w3.w,v3,a3);
    }
    float4* red = smbuf;                // f[0..1024), disjoint from rows
    red[tid] = make_float4(a0, a1, a2, a3);
    __syncthreads();
    int jj = tid >> 6, dd = tid & 63;
    float4 r0 = red[dd], r1 = red[64+dd], r2 = red[128+dd], r3 = red[192+dd];
    float s;
    if (jj == 0)      s = r0.x + r1.x + r2.x + r3.x;
    else if (jj == 1) s = r0.y + r1.y + r2.y + r3.y;
    else if (jj == 2) s = r0.z + r1.z + r2.z + r3.z;
    else              s = r0.w + r1.w + r2.w + r3.w;
    if (j0 + jj > NJ) s = 0.f;
    WVp[(size_t)mc*73728 + ((size_t)bh*72 + j0 + jj)*64 + dd] = s;
  } else {                              // ---- k4 ----
    int gid = bid - 1152;
    int bh = gid >> 5;  int m0 = (gid & 31) << 5;
    int b = bh >> 3, h = bh & 7;
    float* qs   = f;                    // 35*64
    float* ts   = f + 2240;
    float* sc   = f + 4480;             // 32*73
    float* invs = f + 6816;             // 32
    for (int i = tid; i < NTOP*64; i += 256) {
      int j = i >> 6, e = i & 63;
      qs[i] = q  [(((size_t)(b*1024 + St [bh*40 + j])*8 + h) << 6) + e];
      ts[i] = tfq[(((size_t)(b*1024 + Stf[bh*40 + j])*8 + h) << 6) + e];
    }
    __syncthreads();
    int mi = tid & 31, g = tid >> 5;
    int br = g >> 2, g4 = g & 3;
    int m = m0 + mi;
    const float* src = br ? tfq : k;
    float4 kr[16];
    const float4* p = reinterpret_cast<const float4*>(
        src + (((size_t)(b*1024 + m)*8 + h) << 6));
    #pragma unroll
    for (int i = 0; i < 16; ++i) kr[i] = p[i];
    const float4* fs4 = reinterpret_cast<const float4*>(br ? ts : qs);
    int sb = br ? NTOP : 0;
    for (int j = g4; j < NTOP; j += 4) {
      float s = 0.f;
      #pragma unroll
      for (int e4 = 0; e4 < 16; ++e4) {
        float4 qv = fs4[j*16 + e4];
        s += qv.x*kr[e4].x + qv.y*kr[e4].y + qv.z*kr[e4].z + qv.w*kr[e4].w;
      }
      sc[mi*73 + sb + j] = s * 0.125f;
    }
    __syncthreads();
    if (tid < 32) {
      float mx = -1e30f;
      for (int j = 0; j < NJ; ++j) mx = fmaxf(mx, sc[tid*73 + j]);
      float sum = 0.f;
      for (int j = 0; j < NJ; ++j) {
        float e = __expf(sc[tid*73 + j] - mx);
        sc[tid*73 + j] = e; sum += e;
      }
      invs[tid] = 1.0f / sum;
    }
    __syncthreads();
    float* Pb = P + ((size_t)bh*1024 + m0)*72;
    for (int i = tid; i < 32*72; i += 256) {
      int mm = i / 72, j = i - mm*72;
      Pb[i] = (j < NJ) ? sc[mm*73 + j] * invs[mm] : 0.f;
    }
  }
}

// ---------------- D4: k6 per-bh, 512 thr, LDS Wv + transposed P chunk ----------------
__global__ __launch_bounds__(512) void k6_out(
    const float* __restrict__ P, const float* __restrict__ WVp,
    float* __restrict__ out) {
  __shared__ float wv[72*64];           // 18432 B
  __shared__ float Pl[72*68];           // 19584 B
  int bh = blockIdx.x, lc = blockIdx.y;
  int l0 = lc << 6;
  int b = bh >> 3, h = bh & 7;
  int tid = threadIdx.x;
  {
    const float* W0 = WVp + (size_t)bh*4608;
    for (int i = tid; i < 4608; i += 512)
      wv[i] = W0[i] + W0[73728 + i] + W0[147456 + i] + W0[221184 + i];
  }
  {
    const float* Pg = P + ((size_t)bh*1024 + l0)*72;
    for (int i = tid; i < 4608; i += 512) {
      int l = i / 72, j = i - l*72;
      Pl[j*68 + l] = Pg[i];
    }
  }
  __syncthreads();
  int d = tid & 63, lg = tid >> 6;      // 8 l-groups of 8
  int lb = lg << 3;
  float acc[8];
  float base = wv[NJ*64 + d];
  #pragma unroll
  for (int i = 0; i < 8; ++i) acc[i] = base;
  for (int j = 0; j < NJ; ++j) {
    float wvj = wv[j*64 + d];
    const float4* pr = reinterpret_cast<const float4*>(Pl + j*68 + lb);
    float4 p0 = pr[0], p1 = pr[1];
    acc[0] = fmaf(p0.x, wvj, acc[0]); acc[1] = fmaf(p0.y, wvj, acc[1]);
    acc[2] = fmaf(p0.z, wvj, acc[2]); acc[3] = fmaf(p0.w, wvj, acc[3]);
    acc[4] = fmaf(p1.x, wvj, acc[4]); acc[5] = fmaf(p1.y, wvj, acc[5]);
    acc[6] = fmaf(p1.z, wvj, acc[6]); acc[7] = fmaf(p1.w, wvj, acc[7]);
  }
  #pragma unroll
  for (int i = 0; i < 8; ++i) {
    int l = l0 + lb + i;
    out[(((size_t)(b*1024 + l)*8 + h) << 6) + d] = acc[i];
  }
}

extern "C" void kernel_launch(void* const* d_in, const int* in_sizes, int n_in,
                              void* d_out, int out_size, void* d_ws, size_t ws_size,
                              hipStream_t stream) {
  const float* tfq  = (const float*)d_in[0];
  const float* q    = (const float*)d_in[1];
  const float* k    = (const float*)d_in[2];
  const float* v    = (const float*)d_in[3];
  const float* tw   = (const float*)d_in[5];
  const float* tb   = (const float*)d_in[6];
  float* out = (float*)d_out;

  char* ws = (char*)d_ws;
  float* acp  = (float*)(ws);                       // 16,777,216
  int*   St   = (int*)  (ws + 16777216);            // 4 KB
  int*   Stf  = (int*)  (ws + 16781312);            // 4 KB
  float* Wt   = (float*)(ws + 16785408);            // 8,388,608
  float* P    = (float*)(ws + 25174016);            // 4,718,592
  float* WVp  = (float*)(ws + 29892608);            // 1,179,648
  float* amp  = (float*)(ws + 31072256);            // 64 KB
  float* ampTF= (float*)(ws + 31137792);            // 64 KB

  d1_prep<<<2560, 256, 0, stream>>>(q, k, tw, Wt, acp);
  d2a_amp<<<512, 256, 0, stream>>>(acp, tfq, amp, ampTF);
  d2b_topk<<<32, 64, 0, stream>>>(amp, ampTF, St, Stf);
  d3_mix <<<1664, 256, 0, stream>>>(q, k, tfq, Wt, tb, v, St, Stf, WVp, P);
  k6_out <<<dim3(16, 16), 512, 0, stream>>>(P, WVp, out);
}

// Round 4
// 166.938 us; speedup vs baseline: 1.0345x; 1.0345x over previous
//
#include <hip/hip_runtime.h>

// MixSelfAttention (B=2, L=1024, H=8, E=64), float32 in/out. 5 dispatches:
//   D1 d1: kw tile-transpose W -> Wt[2048][1024] FIRST (blocks 0..511, f4 both
//          sides) so its 16MB streams overlap k1 compute (was a 21us tail);
//          k1 circular-corr partials (blocks 512..1535 = bh x eg x tc256),
//          256 thr = 4 t-subchunks x 64 tau-grp, 16 taus/thread, XOR16 LDS,
//          in-block sub-combine -> acp[bh][eg][tc][tau][4e] raw partials (16 MB)
//   D2a: 512 blocks x 256 thr; t: tc-combine+square+e-sum -> amp[16][1024]
//        tf: row norms -> ampTF[16][1024]
//   D2b: 32 blocks x 64 thr; single-wave top-35 -> St / Stf
//   D3 d3: k4 scores+softmax -> P FIRST (blocks 0..511, compute-heavy)
//          | kb Wt-row WVp partials (512..1663, values-scatter latency-heavy)
//   D4 k6: per-bh blocks, 512 thr; Wv=sum_mc WVp staged in LDS + transposed P

#define NTOP 35
#define NJ 70
#define LLMIN (-0x7FFFFFFFFFFFFFFFLL - 1)

static __device__ __forceinline__ void fma4(float4& a, float4 q, float4 k) {
  a.x = fmaf(q.x,k.x,a.x); a.y = fmaf(q.y,k.y,a.y);
  a.z = fmaf(q.z,k.z,a.z); a.w = fmaf(q.w,k.w,a.w);
}
static __device__ __forceinline__ void fadd4(float4& a, float4 b) {
  a.x += b.x; a.y += b.y; a.z += b.z; a.w += b.w;
}

// single-wave top-35 (64-thread block), vals[1024] ready, jax tie-break
static __device__ __forceinline__ void wave_top35(const float* vals, int* out) {
  int lane = threadIdx.x;
  long long kreg[16];
  long long lmax = LLMIN;
  #pragma unroll
  for (int s = 0; s < 16; ++s) {
    int l = (s << 6) + lane;
    long long key = ((long long)(int)__float_as_uint(vals[l]) << 32)
                    | (unsigned int)(1023 - l);
    kreg[s] = key;
    lmax = key > lmax ? key : lmax;
  }
  for (int it = 0; it < NTOP; ++it) {
    long long g = lmax;
    #pragma unroll
    for (int off = 1; off < 64; off <<= 1) {
      long long o = __shfl_xor(g, off);
      g = o > g ? o : g;
    }
    if (lane == 0) out[it] = 1023 - (int)(g & 0xFFFFFFFFLL);
    if (lmax == g) {
      lmax = LLMIN;
      #pragma unroll
      for (int s = 0; s < 16; ++s) {
        if (kreg[s] == g) kreg[s] = LLMIN;
        lmax = kreg[s] > lmax ? kreg[s] : lmax;
      }
    }
  }
}

// XOR16 swizzle: conflict-free for stride-1 (staging) AND stride-16 (window)
static __device__ __forceinline__ int qsw(int r) { return r ^ ((r >> 4) & 7); }

// ---------------- D1: kw (blocks 0..511) | k1 (512..1535), 256 thr ----------------
__global__ __launch_bounds__(256) void d1_prep(
    const float* __restrict__ q, const float* __restrict__ k,
    const float* __restrict__ w,
    float* __restrict__ Wt, float* __restrict__ acp) {
  __shared__ float smem[5200];          // 20.8 KB: QP 1024 f4 + Ks 256 f4 / kw tile
  int bid = blockIdx.x;
  int tid = threadIdx.x;
  if (bid < 512) {                      // ---- kw: f4 tile transpose ----
    int wid = bid;
    int c0 = (wid & 31) << 6, r0 = (wid >> 5) << 6;
    float* tile = smem;                 // 64 x 68 floats = 4352 < 5200
    #pragma unroll
    for (int s = 0; s < 4; ++s) {
      int idx = (s << 8) + tid;         // 0..1023
      int r = idx >> 4, c4 = idx & 15;
      float4 vv = *reinterpret_cast<const float4*>(
          w + (size_t)(r0 + r)*2048 + c0 + (c4 << 2));
      *reinterpret_cast<float4*>(tile + r*68 + (c4 << 2)) = vv;
    }
    __syncthreads();
    #pragma unroll
    for (int s = 0; s < 4; ++s) {
      int idx = (s << 8) + tid;
      int c = idx >> 4, r4 = idx & 15;
      float4 ov;
      ov.x = tile[(r4*4 + 0)*68 + c];
      ov.y = tile[(r4*4 + 1)*68 + c];
      ov.z = tile[(r4*4 + 2)*68 + c];
      ov.w = tile[(r4*4 + 3)*68 + c];
      *reinterpret_cast<float4*>(Wt + (size_t)(c0 + c)*1024 + r0 + (r4 << 2)) = ov;
    }
  } else {                              // ---- k1: (bh, eg, tc) ----
    int kid = bid - 512;
    int bh = kid & 15;  int eg = (kid >> 4) & 15;  int tc = kid >> 8;
    int b = bh >> 3, h = bh & 7;
    float4* QP = reinterpret_cast<float4*>(smem);        // 1024, XOR16 swizzle
    float4* Ks = QP + 1024;                              // 256 (this tc's t's)
    const float* qb  = q + (size_t)b*524288 + h*64 + eg*4;
    const float* kbp = k + (size_t)b*524288 + h*64 + eg*4;
    for (int r = tid; r < 1024; r += 256)
      QP[qsw(r)] = *reinterpret_cast<const float4*>(qb + (size_t)r*512);
    Ks[tid] = *reinterpret_cast<const float4*>(kbp + (size_t)((tc << 8) + tid)*512);
    __syncthreads();
    int sub = tid >> 6, tg = tid & 63;  // 4 t-subchunks x 64 tau-groups
    int tb = tg << 4;                   // 16 taus per thread
    int tstart = (tc << 8) + (sub << 6);// absolute t in [tstart, tstart+64)
    float4 acc[16], wnd[16];
    #pragma unroll
    for (int i = 0; i < 16; ++i) {
      acc[i] = make_float4(0,0,0,0);
      int r = (tstart + tb + i) & 1023;
      wnd[i] = QP[qsw(r)];
    }
    int ksb = sub << 6;
    for (int t8 = 0; t8 < 64; t8 += 16) {
      #pragma unroll
      for (int s = 0; s < 16; ++s) {
        float4 kv = Ks[ksb + t8 + s];
        #pragma unroll
        for (int i = 0; i < 16; ++i)
          fma4(acc[i], wnd[(s + i) & 15], kv);  // acc FIXED per tau tb+i
        int rn = (tstart + t8 + s + tb + 16) & 1023;
        wnd[s] = QP[qsw(rn)];                   // overwrite slot t&15
      }
    }
    __syncthreads();                    // QP/Ks dead; reuse for combine tree
    float4* xb = reinterpret_cast<float4*>(smem);   // 1300 f4 avail; use 1152
    // Level 1 (sub 2->0, 3->1), two 8-f4 halves, rows of 9 f4
    #pragma unroll
    for (int half = 0; half < 2; ++half) {
      if (sub >= 2) {
        float4* rp = xb + (sub - 2)*576 + tg*9;
        #pragma unroll
        for (int i = 0; i < 8; ++i) rp[i] = acc[half*8 + i];
      }
      __syncthreads();
      if (sub < 2) {
        const float4* rp = xb + sub*576 + tg*9;
        #pragma unroll
        for (int i = 0; i < 8; ++i) fadd4(acc[half*8 + i], rp[i]);
      }
      __syncthreads();
    }
    // Level 2 (sub 1 -> 0), two halves
    #pragma unroll
    for (int half = 0; half < 2; ++half) {
      if (sub == 1) {
        float4* rp = xb + tg*9;
        #pragma unroll
        for (int i = 0; i < 8; ++i) rp[i] = acc[half*8 + i];
      }
      __syncthreads();
      if (sub == 0) {
        const float4* rp = xb + tg*9;
        #pragma unroll
        for (int i = 0; i < 8; ++i) fadd4(acc[half*8 + i], rp[i]);
      }
      __syncthreads();
    }
    if (sub == 0) {                     // raw 4e partials for this tc chunk
      float4* op = reinterpret_cast<float4*>(acp)
                 + (((size_t)((bh*16 + eg)*4 + tc)) << 10) + tb;
      #pragma unroll
      for (int i = 0; i < 16; ++i) op[i] = acc[i];
    }
  }
}

// ---------------- D2a: amp / tf-norm reduction, 512 blocks x 256 thr ----------------
__global__ __launch_bounds__(256) void d2a_amp(
    const float* __restrict__ acp, const float* __restrict__ tfq,
    float* __restrict__ amp, float* __restrict__ ampTF) {
  __shared__ float red[256];
  int bid = blockIdx.x;
  int tid = threadIdx.x;
  int lane = tid & 63, g = tid >> 6;     // 4 e-groups / 4 row-quarters
  if (bid < 256) {                        // ---- t: tc-combine + square + e-sum ----
    int bh = bid >> 4, tg = bid & 15;
    int tau = (tg << 6) + lane;
    const float4* A = reinterpret_cast<const float4*>(acp);
    float s = 0.f;
    #pragma unroll
    for (int eg4 = 0; eg4 < 4; ++eg4) {
      int eg = (g << 2) + eg4;
      const float4* E = A + (((size_t)(bh*16 + eg)) << 12);
      float4 c0 = E[tau], c1 = E[1024+tau], c2 = E[2048+tau], c3 = E[3072+tau];
      float x = c0.x+c1.x+c2.x+c3.x;
      float y = c0.y+c1.y+c2.y+c3.y;
      float z = c0.z+c1.z+c2.z+c3.z;
      float w = c0.w+c1.w+c2.w+c3.w;
      s += x*x + y*y + z*z + w*w;
    }
    red[tid] = s;
    __syncthreads();
    if (g == 0)
      amp[bh*1024 + tau] = red[lane] + red[64+lane] + red[128+lane] + red[192+lane];
  } else {                                // ---- tf: row norms ----
    int wid = bid - 256;
    int bh = wid >> 4, lg = wid & 15;
    int b = bh >> 3, h = bh & 7;
    int l = (lg << 6) + lane;
    const float4* p = reinterpret_cast<const float4*>(
        tfq + (((size_t)(b*1024 + l)*8 + h) << 6)) + (g << 2);
    float s = 0.f;
    #pragma unroll
    for (int i = 0; i < 4; ++i) {
      float4 vv = p[i];
      s += vv.x*vv.x + vv.y*vv.y + vv.z*vv.z + vv.w*vv.w;
    }
    red[tid] = s;
    __syncthreads();
    if (g == 0)
      ampTF[bh*1024 + l] = red[lane] + red[64+lane] + red[128+lane] + red[192+lane];
  }
}

// ---------------- D2b: top-35 both branches, 32 blocks x 1 wave ----------------
__global__ __launch_bounds__(64) void d2b_topk(
    const float* __restrict__ amp, const float* __restrict__ ampTF,
    int* __restrict__ St, int* __restrict__ Stf) {
  __shared__ float vals[1024];
  int bid = blockIdx.x;
  int tid = threadIdx.x;
  bool isT = bid < 16;
  int bh = isT ? bid : bid - 16;
  const float* src = (isT ? amp : ampTF) + bh*1024;
  #pragma unroll
  for (int s = 0; s < 16; ++s) vals[(s << 6) + tid] = src[(s << 6) + tid];
  __syncthreads();
  wave_top35(vals, (isT ? St : Stf) + bh*40);
}

// ---------------- D3: k4 (blocks 0..511) | kb (512..1663) ----------------
__global__ __launch_bounds__(256) void d3_mix(
    const float* __restrict__ q, const float* __restrict__ k,
    const float* __restrict__ tfq,
    const float* __restrict__ Wt, const float* __restrict__ bias,
    const float* __restrict__ values,
    const int* __restrict__ St, const int* __restrict__ Stf,
    float* __restrict__ WVp, float* __restrict__ P) {
  __shared__ float4 smbuf[1712];        // 27392 B (k4); kb uses first 8 KB
  float* f = reinterpret_cast<float*>(smbuf);
  int bid = blockIdx.x;
  int tid = threadIdx.x;
  if (bid >= 512) {                     // ---- kb: WVp partial, LDS-staged rows ----
    int kbid = bid - 512;
    int jq = kbid / 64;                 // 0..17
    int rem = kbid - jq*64;
    int bh = rem >> 2, mc = rem & 3;
    int b = bh >> 3, h = bh & 7;
    int j0 = jq << 2;
    int mbase = mc << 8;
    float* rows = f + 1024;             // 4 rows x 256 m-chunk = 4 KB
    #pragma unroll
    for (int x = 0; x < 4; ++x) {
      int j = j0 + x;
      const float* pj;
      if (j < NTOP)      pj = Wt + (size_t)St [bh*40 + j]*1024;
      else if (j < NJ)   pj = Wt + (size_t)(1024 + Stf[bh*40 + j-NTOP])*1024;
      else if (j == NJ)  pj = bias;
      else               pj = Wt;       // j==71: garbage, zeroed in epilogue
      rows[(x << 8) + tid] = pj[mbase + tid];
    }
    __syncthreads();
    int d = tid & 63, mp = tid >> 6;    // wave mp owns contiguous m-chunk of 64
    float a0=0.f, a1=0.f, a2=0.f, a3=0.f;
    const float4* r4 = reinterpret_cast<const float4*>(rows);
    const float* vbase = values
        + (((size_t)(b*1024 + mbase + (mp << 6))*8 + h) << 6) + d;
    #pragma unroll 4
    for (int i4 = 0; i4 < 16; ++i4) {
      float4 w0 = r4[       (mp << 4) + i4];
      float4 w1 = r4[ 64  + (mp << 4) + i4];
      float4 w2 = r4[128  + (mp << 4) + i4];
      float4 w3 = r4[192  + (mp << 4) + i4];
      float v0 = vbase[(size_t)((i4 << 2) + 0)*512];
      float v1 = vbase[(size_t)((i4 << 2) + 1)*512];
      float v2 = vbase[(size_t)((i4 << 2) + 2)*512];
      float v3 = vbase[(size_t)((i4 << 2) + 3)*512];
      a0 = fmaf(w0.x,v0,a0); a0 = fmaf(w0.y,v1,a0);
      a0 = fmaf(w0.z,v2,a0); a0 = fmaf(w0.w,v3,a0);
      a1 = fmaf(w1.x,v0,a1); a1 = fmaf(w1.y,v1,a1);
      a1 = fmaf(w1.z,v2,a1); a1 = fmaf(w1.w,v3,a1);
      a2 = fmaf(w2.x,v0,a2); a2 = fmaf(w2.y,v1,a2);
      a2 = fmaf(w2.z,v2,a2); a2 = fmaf(w2.w,v3,a2);
      a3 = fmaf(w3.x,v0,a3); a3 = fmaf(w3.y,v1,a3);
      a3 = fmaf(w3.z,v2,a3); a3 = fmaf(w3.w,v3,a3);
    }
    float4* red = smbuf;                // f[0..1024), disjoint from rows
    red[tid] = make_float4(a0, a1, a2, a3);
    __syncthreads();
    int jj = tid >> 6, dd = tid & 63;
    float4 r0 = red[dd], r1 = red[64+dd], r2 = red[128+dd], r3 = red[192+dd];
    float s;
    if (jj == 0)      s = r0.x + r1.x + r2.x + r3.x;
    else if (jj == 1) s = r0.y + r1.y + r2.y + r3.y;
    else if (jj == 2) s = r0.z + r1.z + r2.z + r3.z;
    else              s = r0.w + r1.w + r2.w + r3.w;
    if (j0 + jj > NJ) s = 0.f;
    WVp[(size_t)mc*73728 + ((size_t)bh*72 + j0 + jj)*64 + dd] = s;
  } else {                              // ---- k4 ----
    int gid = bid;
    int bh = gid >> 5;  int m0 = (gid & 31) << 5;
    int b = bh >> 3, h = bh & 7;
    float* qs   = f;                    // 35*64
    float* ts   = f + 2240;
    float* sc   = f + 4480;             // 32*73
    float* invs = f + 6816;             // 32
    for (int i = tid; i < NTOP*64; i += 256) {
      int j = i >> 6, e = i & 63;
      qs[i] = q  [(((size_t)(b*1024 + St [bh*40 + j])*8 + h) << 6) + e];
      ts[i] = tfq[(((size_t)(b*1024 + Stf[bh*40 + j])*8 + h) << 6) + e];
    }
    __syncthreads();
    int mi = tid & 31, g = tid >> 5;
    int br = g >> 2, g4 = g & 3;
    int m = m0 + mi;
    const float* src = br ? tfq : k;
    float4 kr[16];
    const float4* p = reinterpret_cast<const float4*>(
        src + (((size_t)(b*1024 + m)*8 + h) << 6));
    #pragma unroll
    for (int i = 0; i < 16; ++i) kr[i] = p[i];
    const float4* fs4 = reinterpret_cast<const float4*>(br ? ts : qs);
    int sb = br ? NTOP : 0;
    for (int j = g4; j < NTOP; j += 4) {
      float s = 0.f;
      #pragma unroll
      for (int e4 = 0; e4 < 16; ++e4) {
        float4 qv = fs4[j*16 + e4];
        s += qv.x*kr[e4].x + qv.y*kr[e4].y + qv.z*kr[e4].z + qv.w*kr[e4].w;
      }
      sc[mi*73 + sb + j] = s * 0.125f;
    }
    __syncthreads();
    if (tid < 32) {
      float mx = -1e30f;
      for (int j = 0; j < NJ; ++j) mx = fmaxf(mx, sc[tid*73 + j]);
      float sum = 0.f;
      for (int j = 0; j < NJ; ++j) {
        float e = __expf(sc[tid*73 + j] - mx);
        sc[tid*73 + j] = e; sum += e;
      }
      invs[tid] = 1.0f / sum;
    }
    __syncthreads();
    float* Pb = P + ((size_t)bh*1024 + m0)*72;
    for (int i = tid; i < 32*72; i += 256) {
      int mm = i / 72, j = i - mm*72;
      Pb[i] = (j < NJ) ? sc[mm*73 + j] * invs[mm] : 0.f;
    }
  }
}

// ---------------- D4: k6 per-bh, 512 thr, LDS Wv + transposed P chunk ----------------
__global__ __launch_bounds__(512) void k6_out(
    const float* __restrict__ P, const float* __restrict__ WVp,
    float* __restrict__ out) {
  __shared__ float wv[72*64];           // 18432 B
  __shared__ float Pl[72*68];           // 19584 B
  int bh = blockIdx.x, lc = blockIdx.y;
  int l0 = lc << 6;
  int b = bh >> 3, h = bh & 7;
  int tid = threadIdx.x;
  {
    const float* W0 = WVp + (size_t)bh*4608;
    for (int i = tid; i < 4608; i += 512)
      wv[i] = W0[i] + W0[73728 + i] + W0[147456 + i] + W0[221184 + i];
  }
  {
    const float* Pg = P + ((size_t)bh*1024 + l0)*72;
    for (int i = tid; i < 4608; i += 512) {
      int l = i / 72, j = i - l*72;
      Pl[j*68 + l] = Pg[i];
    }
  }
  __syncthreads();
  int d = tid & 63, lg = tid >> 6;      // 8 l-groups of 8
  int lb = lg << 3;
  float acc[8];
  float base = wv[NJ*64 + d];
  #pragma unroll
  for (int i = 0; i < 8; ++i) acc[i] = base;
  for (int j = 0; j < NJ; ++j) {
    float wvj = wv[j*64 + d];
    const float4* pr = reinterpret_cast<const float4*>(Pl + j*68 + lb);
    float4 p0 = pr[0], p1 = pr[1];
    acc[0] = fmaf(p0.x, wvj, acc[0]); acc[1] = fmaf(p0.y, wvj, acc[1]);
    acc[2] = fmaf(p0.z, wvj, acc[2]); acc[3] = fmaf(p0.w, wvj, acc[3]);
    acc[4] = fmaf(p1.x, wvj, acc[4]); acc[5] = fmaf(p1.y, wvj, acc[5]);
    acc[6] = fmaf(p1.z, wvj, acc[6]); acc[7] = fmaf(p1.w, wvj, acc[7]);
  }
  #pragma unroll
  for (int i = 0; i < 8; ++i) {
    int l = l0 + lb + i;
    out[(((size_t)(b*1024 + l)*8 + h) << 6) + d] = acc[i];
  }
}

extern "C" void kernel_launch(void* const* d_in, const int* in_sizes, int n_in,
                              void* d_out, int out_size, void* d_ws, size_t ws_size,
                              hipStream_t stream) {
  const float* tfq  = (const float*)d_in[0];
  const float* q    = (const float*)d_in[1];
  const float* k    = (const float*)d_in[2];
  const float* v    = (const float*)d_in[3];
  const float* tw   = (const float*)d_in[5];
  const float* tb   = (const float*)d_in[6];
  float* out = (float*)d_out;

  char* ws = (char*)d_ws;
  float* acp  = (float*)(ws);                       // 16,777,216
  int*   St   = (int*)  (ws + 16777216);            // 4 KB
  int*   Stf  = (int*)  (ws + 16781312);            // 4 KB
  float* Wt   = (float*)(ws + 16785408);            // 8,388,608
  float* P    = (float*)(ws + 25174016);            // 4,718,592
  float* WVp  = (float*)(ws + 29892608);            // 1,179,648
  float* amp  = (float*)(ws + 31072256);            // 64 KB
  float* ampTF= (float*)(ws + 31137792);            // 64 KB

  d1_prep<<<1536, 256, 0, stream>>>(q, k, tw, Wt, acp);
  d2a_amp<<<512, 256, 0, stream>>>(acp, tfq, amp, ampTF);
  d2b_topk<<<32, 64, 0, stream>>>(amp, ampTF, St, Stf);
  d3_mix <<<1664, 256, 0, stream>>>(q, k, tfq, Wt, tb, v, St, Stf, WVp, P);
  k6_out <<<dim3(16, 16), 512, 0, stream>>>(P, WVp, out);
}